// Round 2
// baseline (4844.998 us; speedup 1.0000x reference)
//
#include <hip/hip_runtime.h>
#include <hip/hip_bf16.h>
#include <cstdint>

// CharRNN fused kernel, round 2 — MI355X (gfx950).
//
// Topology: 16 clusters x 16 members = 256 wgs (1 per CU, co-resident).
// Cluster c owns batch rows [8c,8c+8). Member m owns hidden outputs
// [32m,32m+32) (W_hh rows register-resident as bf16 hi+lo fragments) and
// vocab rows [8m,8m+8) of W_fc (register-resident bf16).
//
// Numerics (round-1 error 0.447 was bf16 noise x ~500 near-critical
// recurrence amplification):
//  - W_hh = w_hi + w_lo (bf16 pair, rel err ~2^-18) -> 3-term MFMA.
//  - h exchanged as 21-bit fixed point (abs err 2^-20) + 11-bit gen tag
//    in one u32; reader splits h into bf16 hi+lo fragments.
//  - xp table, accumulation, tanh all fp32.
//
// Exchange: tag-validated relaxed agent-scope atomics, generation-parity
// double buffer in d_ws (512 KB). 0xAA poison tag field = 682 ~=~ only
// gens 1,2 read possibly-unwritten slots -> no collision.

typedef short bf16x8 __attribute__((ext_vector_type(8)));
typedef float f32x4 __attribute__((ext_vector_type(4)));

#define VOCAB 128
#define EMB   16
#define HID   512
#define TT    1024
#define CLW   16
#define JC    32          // hidden outputs per wg
#define VC    8           // vocab rows per wg
#define BB    8           // batch rows per cluster
#define NCL   16
#define NWG   256
#define WROW  520         // padded bf16 row (512+8): 2-way-free LDS banking
#define BUFW  (NCL * BB * HID)   // 65536 words per generation buffer

struct StageMem {                       // setup-only (overlaid by RunMem)
  unsigned short w_hi[JC * WROW];       // 33280 B
  unsigned short w_lo[JC * WROW];       // 33280 B
  unsigned short wfc[VC * WROW];        //  8320 B
  unsigned short pad[4608];             // push LDS ~84 KB -> exactly 1 wg/CU
};
struct RunMem {
  unsigned short a_hi[BB * WROW];       // h state hi  8320 B
  unsigned short a_lo[BB * WROW];       // h state lo  8320 B
  float ep[VOCAB * JC];                 // xp table   16384 B
  float red[2 * 32 * 4];                // logits partials
  float bfcs[VC];
  unsigned char xtok[BB * TT];          // token ids   8192 B
};

__device__ __forceinline__ unsigned short f2bf(float f) {
  uint32_t u = __builtin_bit_cast(uint32_t, f);
  u += 0x7FFFu + ((u >> 16) & 1u);
  return (unsigned short)(u >> 16);
}
__device__ __forceinline__ float bf2f(unsigned short s) {
  uint32_t u = (uint32_t)s << 16;
  return __builtin_bit_cast(float, u);
}
__device__ __forceinline__ float ftanh(float z) {
  z = fminf(15.f, fmaxf(-15.f, z));
  float e = __expf(2.f * z);
  return (e - 1.f) * __builtin_amdgcn_rcpf(e + 1.f);
}

__global__ __launch_bounds__(256, 1) void charrnn_kernel(
    const int* __restrict__ xin,
    const float* __restrict__ emb,
    const float* __restrict__ wih,
    const float* __restrict__ whh,
    const float* __restrict__ bih,
    const float* __restrict__ bhh,
    const float* __restrict__ wfc,
    const float* __restrict__ bfc,
    float* __restrict__ out,
    uint32_t* __restrict__ hx)
{
  __shared__ union SM { StageMem s; RunMem r; } sm;

  const int tid  = threadIdx.x;
  const int wave = tid >> 6;
  const int lane = tid & 63;
  const int col  = lane & 15;
  const int quad = lane >> 4;
  const int cl   = blockIdx.x & 15;   // members of a cluster: blockIdx = cl + 16m
  const int m    = blockIdx.x >> 4;   // -> all on XCD (cl&7) under round-robin

  // ---- phase 1: stage W_hh hi/lo + W_fc chunk into LDS ----
  for (int i = tid; i < JC * HID; i += 256) {
    int jl = i >> 9, k = i & 511;
    float w = whh[(m * JC + jl) * HID + k];
    unsigned short h = f2bf(w);
    sm.s.w_hi[jl * WROW + k] = h;
    sm.s.w_lo[jl * WROW + k] = f2bf(w - bf2f(h));
  }
  for (int i = tid; i < VC * HID; i += 256) {
    int v = i >> 9, k = i & 511;
    sm.s.wfc[v * WROW + k] = f2bf(wfc[(m * VC + v) * HID + k]);
  }
  __syncthreads();

  // ---- phase 2: W fragments -> registers (waves 0,1 only use them) ----
  bf16x8 wfh[16], wfl[16], wfcf[16];
  if (wave < 2) {
    const int kf = quad * 8;
    const int bo = (wave * 16 + col) * WROW + kf;
    const int fo = (col & 7) * WROW + kf;
    #pragma unroll
    for (int ks = 0; ks < 16; ++ks) {
      wfh[ks]  = *(const bf16x8*)&sm.s.w_hi[bo + ks * 32];
      wfl[ks]  = *(const bf16x8*)&sm.s.w_lo[bo + ks * 32];
      wfcf[ks] = *(const bf16x8*)&sm.s.wfc[fo + ks * 32];
    }
  }
  __syncthreads();

  // ---- phase 3: overlay -> run memory: ep table, tokens, h0=0 ----
  for (int i = tid; i < BB * WROW; i += 256) { sm.r.a_hi[i] = 0; sm.r.a_lo[i] = 0; }
  for (int i = tid; i < VOCAB * JC; i += 256) {
    int v = i >> 5, jl = i & 31;
    int jg = m * JC + jl;
    float s = bih[jg] + bhh[jg];
    #pragma unroll
    for (int e = 0; e < EMB; ++e) s += emb[v * EMB + e] * wih[jg * EMB + e];
    sm.r.ep[v * JC + jl] = s;
  }
  for (int i = tid; i < BB * TT; i += 256) {
    int b = i >> 10, t = i & 1023;
    sm.r.xtok[i] = (unsigned char)xin[(cl * BB + b) * TT + t];
  }
  if (tid < VC) sm.r.bfcs[tid] = bfc[m * VC + tid];
  __syncthreads();

  // ---- main time loop ----
  const int aoff = (col & 7) * WROW + quad * 8;  // A row = batch (rows 8-15 dup)
  const int pb   = tid >> 5;                     // poll: batch row
  const int pk0  = (tid & 31) << 4;              // poll: 16 consecutive k
  uint32_t* const hx0 = hx + (cl * BB + pb) * HID + pk0;
  const float rcp20 = 1.f / 1048576.f;

  #pragma unroll 1
  for (int t = 0; t <= TT + 1; ++t) {
    // A) logits reduce + store for time t-2 (wave 2; partials from iter t-1)
    if (t >= 2 && wave == 2 && lane < 32 && col < 8) {
      #pragma unroll
      for (int i = 0; i < 4; ++i) {
        int b = quad * 4 + i;
        float s = sm.r.red[lane * 4 + i] + sm.r.red[128 + lane * 4 + i] + sm.r.bfcs[col];
        out[((size_t)(cl * BB + b) * TT + (t - 2)) * VOCAB + m * VC + col] = s;
      }
    }

    // B) poll gen t (tag-validated), convert fixed-point -> bf16 hi/lo in LDS
    if (t >= 1 && t <= TT) {
      uint32_t* p = hx0 + (t & 1) * BUFW;
      const uint32_t tag = (uint32_t)t;
      uint32_t v[16];
      for (;;) {
        uint32_t bad = 0;
        #pragma unroll
        for (int i = 0; i < 16; ++i)
          v[i] = __hip_atomic_load(p + i, __ATOMIC_RELAXED, __HIP_MEMORY_SCOPE_AGENT);
        #pragma unroll
        for (int i = 0; i < 16; ++i) bad |= (v[i] ^ tag);
        if ((bad & 0x7FFu) == 0) break;
      }
      uint32_t hw[8], lw[8];
      #pragma unroll
      for (int i = 0; i < 16; ++i) {
        float h = (float)(((int)v[i]) >> 11) * rcp20;
        uint32_t u  = __builtin_bit_cast(uint32_t, h);
        uint32_t uh = u & 0xFFFF0000u;                       // truncate hi
        float l = h - __builtin_bit_cast(float, uh);         // exact residual
        uint32_t ul = __builtin_bit_cast(uint32_t, l);
        if (i & 1) { hw[i >> 1] |= uh;        lw[i >> 1] |= ul & 0xFFFF0000u; }
        else       { hw[i >> 1]  = uh >> 16;  lw[i >> 1]  = ul >> 16; }
      }
      uint32_t* dh = (uint32_t*)&sm.r.a_hi[pb * WROW + pk0];
      uint32_t* dl = (uint32_t*)&sm.r.a_lo[pb * WROW + pk0];
      #pragma unroll
      for (int i = 0; i < 8; ++i) { dh[i] = hw[i]; dl[i] = lw[i]; }
    }
    __syncthreads();  // #1: lds_a(gen t) ready

    // C) compute (waves 0,1): 3-term recurrence + 1 logits term each
    if (t <= TT && wave < 2) {
      f32x4 acc0 = {0.f,0.f,0.f,0.f}, acc1 = {0.f,0.f,0.f,0.f};
      f32x4 acc2 = {0.f,0.f,0.f,0.f}, lacc = {0.f,0.f,0.f,0.f};
      #pragma unroll
      for (int ks = 0; ks < 16; ++ks) {
        bf16x8 ah = *(const bf16x8*)&sm.r.a_hi[aoff + ks * 32];
        bf16x8 al = *(const bf16x8*)&sm.r.a_lo[aoff + ks * 32];
        acc0 = __builtin_amdgcn_mfma_f32_16x16x32_bf16(ah, wfh[ks], acc0, 0, 0, 0);
        acc1 = __builtin_amdgcn_mfma_f32_16x16x32_bf16(al, wfh[ks], acc1, 0, 0, 0);
        acc2 = __builtin_amdgcn_mfma_f32_16x16x32_bf16(ah, wfl[ks], acc2, 0, 0, 0);
        lacc = __builtin_amdgcn_mfma_f32_16x16x32_bf16(wave ? al : ah, wfcf[ks], lacc, 0, 0, 0);
      }
      if (lane < 32) {
        *(f32x4*)&sm.r.red[wave * 128 + lane * 4] = lacc;   // logits partial (time t-1)
        if (t < TT) {                                       // publish gen t+1
          const int jl = wave * 16 + col;
          const uint32_t tag = (uint32_t)(t + 1);
          uint32_t* wbase = hx + ((t + 1) & 1) * BUFW + (cl * BB) * HID + m * JC + jl;
          #pragma unroll
          for (int i = 0; i < 4; ++i) {
            int b = quad * 4 + i;
            float z = acc0[i] + acc1[i] + acc2[i]
                    + sm.r.ep[(int)sm.r.xtok[b * TT + t] * JC + jl];
            float h = ftanh(z);
            int q = __float2int_rn(h * 1048576.f);
            q = max(min(q, 1048575), -1048576);
            __hip_atomic_store(wbase + b * HID, ((uint32_t)q << 11) | tag,
                               __ATOMIC_RELAXED, __HIP_MEMORY_SCOPE_AGENT);
          }
        }
      }
    }
    __syncthreads();  // #2: lds_a consumed; red published
  }
}

extern "C" void kernel_launch(void* const* d_in, const int* in_sizes, int n_in,
                              void* d_out, int out_size, void* d_ws, size_t ws_size,
                              hipStream_t stream) {
  (void)in_sizes; (void)n_in; (void)out_size;
  if (ws_size < (size_t)2 * BUFW * sizeof(uint32_t)) return;  // 512 KB scratch

  const int*   x    = (const int*)d_in[0];
  const float* embp = (const float*)d_in[1];
  const float* W_ih = (const float*)d_in[2];
  const float* W_hh = (const float*)d_in[3];
  const float* b_ih = (const float*)d_in[4];
  const float* b_hh = (const float*)d_in[5];
  const float* W_fc = (const float*)d_in[6];
  const float* b_fc = (const float*)d_in[7];

  charrnn_kernel<<<NWG, 256, 0, stream>>>(x, embp, W_ih, W_hh, b_ih, b_hh, W_fc, b_fc,
                                          (float*)d_out, (uint32_t*)d_ws);
}